// Round 8
// baseline (1152.066 us; speedup 1.0000x reference)
//
#include <hip/hip_runtime.h>
#include <stdint.h>

#define GLOBAL_AS __attribute__((address_space(1)))
#define LDS_AS    __attribute__((address_space(3)))

typedef __attribute__((ext_vector_type(8))) short  short8;   // 8 bf16 = 4 VGPRs
typedef __attribute__((ext_vector_type(4))) float  floatx4;

static constexpr int B_   = 4096;
static constexpr int T_   = 28;
static constexpr int IN_  = 28;
static constexpr int H_   = 1024;
static constexpr int G4_  = 4096;   // 4*H
static constexpr int OUT_ = 10;
static constexpr int NT_  = 16;     // K-tiles of 64 over H=1024

// ---------- small helpers ----------
__device__ __forceinline__ float bf2f(unsigned short u) {
  union { uint32_t i; float f; } v; v.i = ((uint32_t)u) << 16; return v.f;
}
__device__ __forceinline__ unsigned short f2bf(float f) {  // RTNE
  union { float f; uint32_t i; } v; v.f = f;
  uint32_t x = v.i;
  uint32_t lsb = (x >> 16) & 1u;
  x += 0x7fffu + lsb;
  return (unsigned short)(x >> 16);
}
__device__ __forceinline__ float sigm(float x) {
  return __builtin_amdgcn_rcpf(1.f + __builtin_amdgcn_exp2f(-1.4426950408889634f * x));
}
__device__ __forceinline__ float tanh_f(float x) {
  return 1.f - 2.f * __builtin_amdgcn_rcpf(1.f + __builtin_amdgcn_exp2f(2.8853900817779268f * x));
}
__device__ __forceinline__ void stage16(const unsigned short* g, unsigned short* l) {
  __builtin_amdgcn_global_load_lds(
      (const GLOBAL_AS uint32_t*)g, (LDS_AS uint32_t*)l, 16, 0, 0);
}

// ---------- prologue: x -> bf16 [T][B][32] (k padded 28->32 with zeros) ----------
__global__ __launch_bounds__(256) void conv_x_kernel(const float* __restrict__ x,
                                                     unsigned short* __restrict__ xb) {
  int row = blockIdx.x * 256 + threadIdx.x;   // row = t*4096 + b
  int t  = row >> 12;
  int bb = row & 4095;
  const float* src = x + (bb * T_ + t) * IN_;
  unsigned short* dst = xb + row * 32;
#pragma unroll
  for (int k = 0; k < IN_; ++k) dst[k] = f2bf(src[k]);
  dst[28] = 0; dst[29] = 0; dst[30] = 0; dst[31] = 0;
}

// ---------- prologue: W_hh [1024][4096] fp32 -> Wp [4096][1024] bf16, transposed+interleaved ----------
// permuted n = g64*64 + gate*16 + hw  <->  orig col = gate*1024 + g64*16 + hw
__global__ __launch_bounds__(256) void perm_whh_kernel(const float* __restrict__ whh,
                                                       unsigned short* __restrict__ wp) {
  __shared__ float lds[64][17];
  int g64  = blockIdx.x >> 2;
  int gate = blockIdx.x & 3;
  int oc0  = gate * H_ + g64 * 16;
  int n0   = g64 * 64 + gate * 16;
  int tid  = threadIdx.x;
  for (int kc = 0; kc < 16; ++kc) {
    int k0 = kc * 64;
    __syncthreads();
#pragma unroll
    for (int e = 0; e < 4; ++e) {
      int idx = e * 256 + tid;
      int k = idx >> 4, cc = idx & 15;
      lds[k][cc] = whh[(k0 + k) * G4_ + oc0 + cc];
    }
    __syncthreads();
#pragma unroll
    for (int e = 0; e < 4; ++e) {
      int idx = e * 256 + tid;
      int n = idx >> 6, kk = idx & 63;
      wp[(n0 + n) * H_ + k0 + kk] = f2bf(lds[kk][n]);
    }
  }
}

// ---------- prologue: W_ih [28][4096] -> Wip [4096][32] bf16 transposed+interleaved ----------
__global__ __launch_bounds__(256) void perm_wih_kernel(const float* __restrict__ wih,
                                                       unsigned short* __restrict__ wip) {
  __shared__ float lds[28][17];
  int g64  = blockIdx.x >> 2;
  int gate = blockIdx.x & 3;
  int oc0  = gate * H_ + g64 * 16;
  int n0   = g64 * 64 + gate * 16;
  int tid  = threadIdx.x;
  for (int idx = tid; idx < 448; idx += 256) {
    int k = idx >> 4, cc = idx & 15;
    lds[k][cc] = wih[k * G4_ + oc0 + cc];
  }
  __syncthreads();
#pragma unroll
  for (int e = 0; e < 2; ++e) {
    int idx = e * 256 + tid;
    int n = idx >> 5, kk = idx & 31;
    wip[(n0 + n) * 32 + kk] = (kk < IN_) ? f2bf(lds[kk][n]) : (unsigned short)0;
  }
}

// ================== LSTM step: 256x256 tile, m201-style 8-phase / 2-K-tile schedule ==================
// 8 waves (2M x 4N), per-wave 128x64, BK=64. Phase = {delta-operand ds_reads (4 or 8 b128);
// stage 1 chunk-pair; [vmcnt(6) at ph4/ph8]; BAR; lgkmcnt(0); 16 MFMA; BAR}.
// CHUNK<->QUADRANT MAP (round-8 fix): A(mh0)=chunks{0,2}, A(mh1)={1,3}; B(nh0)={0,1}, B(nh1)={2,3}.
// Stage at phase p the chunk-set whose prior-tile copy was READ at phase p-1:
//   phE1->B{0,1}, phE2->A{0,2}, phE3->B{2,3}, phE4->A{1,3}  (O phases mirrored).
// vmcnt(6) leaves newest 3 chunk-pairs in flight; derived per-phase: every ds_read's
// backing DMA retired >=1 counted-vmcnt earlier (incl. kt=14 tail with vmcnt(0)).
__global__ __launch_bounds__(512, 2) void lstm_step_kernel(
    const unsigned short* __restrict__ hprev,   // [B][H] bf16
    const unsigned short* __restrict__ wp,      // [4096][1024] bf16 (permuted^T)
    const unsigned short* __restrict__ xbt,     // [B][32] bf16 (this t)
    const unsigned short* __restrict__ wip,     // [4096][32] bf16 (permuted^T)
    const float* __restrict__ bias,             // [4096] original gate order
    float* __restrict__ cst,                    // [B][H] fp32
    unsigned short* __restrict__ hnext,         // [B][H] bf16
    int first) {
  __shared__ __align__(16) unsigned short lds[65536];   // 128 KiB: 2 x (A 32KB | B 32KB)

  const int tid = threadIdx.x;           // 0..511
  const int w   = tid >> 6;              // wave 0..7
  const int l   = tid & 63;
  const int wm  = w >> 2;                // 0..1  (M half)
  const int wn  = w & 3;                 // 0..3  (N quarter)
  const int lc  = l & 15;
  const int lk  = l >> 4;                // 0..3

  // XCD-aware bijective block swizzle (256 = 8*32)
  const int hid = blockIdx.x;
  const int lid = (hid & 7) * 32 + (hid >> 3);
  const int bx  = lid & 15, by = lid >> 4;
  const int m0  = bx * 256;              // batch rows
  const int n0  = by * 256;              // permuted gate cols

  const int swz  = (lc & 7) << 4;        // ds_read byte swizzle (main, 128B rows)
  const int swzx = (lc & 3) << 4;        // x-tile (64B rows)

  // ---- staging per-thread constants ----
  const int r8  = tid >> 3;              // main chunk-local row 0..63
  const int c8  = (tid & 7) * 8;         // ushort col within 64
  const int c8s = c8 ^ ((r8 & 7) * 8);   // pre-swizzled source col
  const size_t aoff = (size_t)(m0 + r8) * H_ + c8s;
  const int bwn_low = r8 >> 5;
  const int bc31    = r8 & 31;
  const int rx   = tid >> 2;             // x chunk-local row 0..127
  const int cx8  = (tid & 3) * 8;
  const int cx8s = cx8 ^ ((rx & 3) * 8);

  auto stageA = [&](int bufu, int kt, int i) {
    stage16(hprev + aoff + (size_t)i * (64 * H_) + kt * 64,
            lds + bufu + i * 4096 + tid * 8);
  };
  auto stageB = [&](int bufu, int kt, int j) {
    int col = n0 + (((j & 1) * 2 + bwn_low) * 64) + ((j >> 1) * 32) + bc31;
    stage16(wp + (size_t)col * H_ + c8s + kt * 64,
            lds + bufu + 16384 + j * 4096 + tid * 8);
  };
  auto stageXA = [&](int half) {
    int row = half * 128 + rx;
    stage16(xbt + (size_t)(m0 + row) * 32 + cx8s,
            lds + 32768 + half * 4096 + tid * 8);
  };
  auto stageXB = [&](int half) {
    int col = n0 + (rx >> 5) * 64 + half * 32 + (rx & 31);
    stage16(wip + (size_t)col * 32 + cx8s,
            lds + 32768 + 8192 + half * 4096 + tid * 8);
  };
  auto ldsr = [&](int byteoff) -> short8 {
    return *reinterpret_cast<const short8*>(reinterpret_cast<const char*>(lds) + byteoff);
  };

  floatx4 acc[8][4];
#pragma unroll
  for (int i = 0; i < 8; ++i)
#pragma unroll
    for (int j = 0; j < 4; ++j) acc[i][j] = (floatx4){0.f, 0.f, 0.f, 0.f};

  // fragment registers: one A set + two B sets (ping-pong across tile boundary) = 64 VGPR
  short8 a[4][2], bA[2][2], bB[2][2];

#define LOAD_A_TO(ARR, PB, MH)                                                       \
  _Pragma("unroll") for (int m_ = 0; m_ < 4; ++m_)                                   \
  _Pragma("unroll") for (int k_ = 0; k_ < 2; ++k_)                                   \
    ARR[m_][k_] = ldsr((PB) + (wm * 128 + (MH) * 64 + m_ * 16 + lc) * 128 +          \
                       ((k_ * 64 + lk * 16) ^ swz));

#define LOAD_B_TO(ARR, PB, NH)                                                       \
  _Pragma("unroll") for (int n_ = 0; n_ < 2; ++n_)                                   \
  _Pragma("unroll") for (int k_ = 0; k_ < 2; ++k_)                                   \
    ARR[n_][k_] = ldsr((PB) + 32768 + ((NH) * 128 + wn * 32 + n_ * 16 + lc) * 128 +  \
                       ((k_ * 64 + lk * 16) ^ swz));

#define MFMA_Q(AR, BR, MH, NH)                                                       \
  __builtin_amdgcn_s_setprio(1);                                                     \
  _Pragma("unroll") for (int m_ = 0; m_ < 4; ++m_)                                   \
  _Pragma("unroll") for (int n_ = 0; n_ < 2; ++n_)                                   \
  _Pragma("unroll") for (int k_ = 0; k_ < 2; ++k_)                                   \
    acc[(MH) * 4 + m_][(NH) * 2 + n_] = __builtin_amdgcn_mfma_f32_16x16x32_bf16(     \
        AR[m_][k_], BR[n_][k_], acc[(MH) * 4 + m_][(NH) * 2 + n_], 0, 0, 0);         \
  __builtin_amdgcn_s_setprio(0);

// mid-phase sync: pin reads+stages before barrier; drain LDS reads after; MFMA can't hoist (rule 18)
#define SYNC_MID                                                                     \
  __builtin_amdgcn_sched_barrier(0);                                                 \
  __builtin_amdgcn_s_barrier();                                                      \
  asm volatile("s_waitcnt lgkmcnt(0)" ::: "memory");                                 \
  __builtin_amdgcn_sched_barrier(0);

#define SYNC_MID_V(VM)                                                               \
  __builtin_amdgcn_sched_barrier(0);                                                 \
  asm volatile("s_waitcnt vmcnt(" #VM ")" ::: "memory");                             \
  __builtin_amdgcn_s_barrier();                                                      \
  asm volatile("s_waitcnt lgkmcnt(0)" ::: "memory");                                 \
  __builtin_amdgcn_sched_barrier(0);

#define SYNC_END                                                                     \
  __builtin_amdgcn_sched_barrier(0);                                                 \
  __builtin_amdgcn_s_barrier();                                                      \
  __builtin_amdgcn_sched_barrier(0);

  if (first) {
    // x-projection only
    stageXA(0); stageXA(1); stageXB(0); stageXB(1);
    SYNC_MID_V(0)
    short8 xb4[4];
#pragma unroll
    for (int nf = 0; nf < 4; ++nf)
      xb4[nf] = ldsr(65536 + 16384 +
                     ((nf >> 1) * 128 + wn * 32 + (nf & 1) * 16 + lc) * 64 +
                     ((lk * 16) ^ swzx));
#pragma unroll
    for (int mf = 0; mf < 8; ++mf) {
      short8 xa = ldsr(65536 + (wm * 128 + mf * 16 + lc) * 64 + ((lk * 16) ^ swzx));
#pragma unroll
      for (int nf = 0; nf < 4; ++nf)
        acc[mf][nf] = __builtin_amdgcn_mfma_f32_16x16x32_bf16(xa, xb4[nf], acc[mf][nf], 0, 0, 0);
    }
  } else {
    // ---- prologue: x (buf1 overlay) + tile0 -> buf0 ----
    stageXA(0); stageXA(1); stageXB(0); stageXB(1);
#pragma unroll
    for (int j = 0; j < 4; ++j) stageB(0, 0, j);
#pragma unroll
    for (int i = 0; i < 4; ++i) stageA(0, 0, i);
    SYNC_MID_V(8)                             // x landed; tile0's 8 in flight
    // ---- x compute (reads buf1 overlay) ----
    {
      short8 xb4[4];
#pragma unroll
      for (int nf = 0; nf < 4; ++nf)
        xb4[nf] = ldsr(65536 + 16384 +
                       ((nf >> 1) * 128 + wn * 32 + (nf & 1) * 16 + lc) * 64 +
                       ((lk * 16) ^ swzx));
      __builtin_amdgcn_s_setprio(1);
#pragma unroll
      for (int mf = 0; mf < 8; ++mf) {
        short8 xa = ldsr(65536 + (wm * 128 + mf * 16 + lc) * 64 + ((lk * 16) ^ swzx));
#pragma unroll
        for (int nf = 0; nf < 4; ++nf)
          acc[mf][nf] = __builtin_amdgcn_mfma_f32_16x16x32_bf16(xa, xb4[nf], acc[mf][nf], 0, 0, 0);
      }
      __builtin_amdgcn_s_setprio(0);
      asm volatile("s_waitcnt lgkmcnt(0)" ::: "memory");  // x reads drained before overlay overwrite
      __builtin_amdgcn_sched_barrier(0);
    }
    SYNC_END                                  // buf1 free for tile1 staging
    // ---- tile1 -> buf1; then full drain ----
#pragma unroll
    for (int j = 0; j < 4; ++j) stageB(32768, 1, j);
#pragma unroll
    for (int i = 0; i < 4; ++i) stageA(32768, 1, i);
    SYNC_MID_V(0)                             // tiles 0,1 fully landed
    // ---- prime: bA = B(0, nh0) ----
    LOAD_B_TO(bA, 0, 0)
    asm volatile("s_waitcnt lgkmcnt(0)" ::: "memory");
    __builtin_amdgcn_sched_barrier(0);
    SYNC_END

    // ---- main loop: 2 K-tiles per iteration (E=kt -> buf0, O=kt+1 -> buf1), 8 phases ----
    for (int kt = 0; kt < NT_; kt += 2) {
      // phE1: read A(E,mh0); stage B{0,1}(E+2) [read at prime/phO4]; MFMA(0,0)=a*bA
      LOAD_A_TO(a, 0, 0)
      if (kt + 2 < NT_) { stageB(0, kt + 2, 0); stageB(0, kt + 2, 1); }
      SYNC_MID
      MFMA_Q(a, bA, 0, 0)
      SYNC_END
      // phE2: read B(E,nh1)->bB; stage A{0,2}(E+2) [read at phE1]; MFMA(0,1)=a*bB
      LOAD_B_TO(bB, 0, 1)
      if (kt + 2 < NT_) { stageA(0, kt + 2, 0); stageA(0, kt + 2, 2); }
      SYNC_MID
      MFMA_Q(a, bB, 0, 1)
      SYNC_END
      // phE3: read A(E,mh1); stage B{2,3}(E+2) [read at phE2]; MFMA(1,1)=a*bB
      LOAD_A_TO(a, 0, 1)
      if (kt + 2 < NT_) { stageB(0, kt + 2, 2); stageB(0, kt + 2, 3); }
      SYNC_MID
      MFMA_Q(a, bB, 1, 1)
      SYNC_END
      // phE4: read B(O,nh0)->bB (buf1); stage A{1,3}(E+2) [read at phE3]; vmcnt; MFMA(1,0)=a*bA
      LOAD_B_TO(bB, 65536, 0)
      if (kt + 2 < NT_) { stageA(0, kt + 2, 1); stageA(0, kt + 2, 3); }
      if (kt == NT_ - 2) { SYNC_MID_V(0) } else { SYNC_MID_V(6) }
      MFMA_Q(a, bA, 1, 0)
      SYNC_END
      // phO1: read A(O,mh0); stage B{0,1}(O+2) [read at phE4]; MFMA(0,0)=a*bB
      LOAD_A_TO(a, 65536, 0)
      if (kt + 3 < NT_) { stageB(32768, kt + 3, 0); stageB(32768, kt + 3, 1); }
      SYNC_MID
      MFMA_Q(a, bB, 0, 0)
      SYNC_END
      // phO2: read B(O,nh1)->bA; stage A{0,2}(O+2) [read at phO1]; MFMA(0,1)=a*bA
      LOAD_B_TO(bA, 65536, 1)
      if (kt + 3 < NT_) { stageA(32768, kt + 3, 0); stageA(32768, kt + 3, 2); }
      SYNC_MID
      MFMA_Q(a, bA, 0, 1)
      SYNC_END
      // phO3: read A(O,mh1); stage B{2,3}(O+2) [read at phO2]; MFMA(1,1)=a*bA
      LOAD_A_TO(a, 65536, 1)
      if (kt + 3 < NT_) { stageB(32768, kt + 3, 2); stageB(32768, kt + 3, 3); }
      SYNC_MID
      MFMA_Q(a, bA, 1, 1)
      SYNC_END
      // phO4: read B(E+2,nh0)->bA (buf0, next iter lead); stage A{1,3}(O+2) [read at phO3]; vmcnt; MFMA(1,0)=a*bB
      LOAD_B_TO(bA, 0, 0)
      if (kt + 3 < NT_) { stageA(32768, kt + 3, 1); stageA(32768, kt + 3, 3); }
      SYNC_MID_V(6)
      MFMA_Q(a, bB, 1, 0)
      SYNC_END
    }
  }

  // ---- epilogue: frag n == gate; fused LSTM cell update ----
  const int jj  = (by * 4 + wn) * 16 + lc;       // h column 0..1023
  const float bi  = bias[jj];
  const float bf_ = bias[H_ + jj];
  const float bg_ = bias[2 * H_ + jj];
  const float bo_ = bias[3 * H_ + jj];
#pragma unroll
  for (int mf = 0; mf < 8; ++mf) {
    const int rbase = m0 + wm * 128 + mf * 16 + lk * 4;
#pragma unroll
    for (int r = 0; r < 4; ++r) {
      const size_t idx = (size_t)(rbase + r) * H_ + jj;
      float ig = sigm(acc[mf][0][r] + bi);
      float fg = sigm(acc[mf][1][r] + bf_);
      float gg = tanh_f(acc[mf][2][r] + bg_);
      float og = sigm(acc[mf][3][r] + bo_);
      float cp = first ? 0.f : cst[idx];
      float cn = fg * cp + ig * gg;
      cst[idx] = cn;
      hnext[idx] = f2bf(og * tanh_f(cn));
    }
  }
#undef LOAD_A_TO
#undef LOAD_B_TO
#undef MFMA_Q
#undef SYNC_MID
#undef SYNC_MID_V
#undef SYNC_END
}

// ---------- classifier: out = h @ Wc + bc ----------
__global__ __launch_bounds__(256) void cls_kernel(const unsigned short* __restrict__ h,
                                                  const float* __restrict__ wc,
                                                  const float* __restrict__ bc,
                                                  float* __restrict__ out) {
  int w = threadIdx.x >> 6, l = threadIdx.x & 63;
  int row = blockIdx.x * 4 + w;
  float acc[OUT_];
#pragma unroll
  for (int o = 0; o < OUT_; ++o) acc[o] = 0.f;
  const unsigned short* hr = h + row * H_;
  for (int k = l; k < H_; k += 64) {
    float hv = bf2f(hr[k]);
#pragma unroll
    for (int o = 0; o < OUT_; ++o) acc[o] += hv * wc[k * OUT_ + o];
  }
#pragma unroll
  for (int o = 0; o < OUT_; ++o) {
    float v = acc[o];
#pragma unroll
    for (int s = 32; s > 0; s >>= 1) v += __shfl_down(v, s, 64);
    if (l == 0) out[row * OUT_ + o] = v + bc[o];
  }
}

extern "C" void kernel_launch(void* const* d_in, const int* in_sizes, int n_in,
                              void* d_out, int out_size, void* d_ws, size_t ws_size,
                              hipStream_t stream) {
  const float* x    = (const float*)d_in[0];
  const float* wih  = (const float*)d_in[1];
  const float* whh  = (const float*)d_in[2];
  const float* bias = (const float*)d_in[3];
  const float* wc   = (const float*)d_in[4];
  const float* bc   = (const float*)d_in[5];
  float* out = (float*)d_out;

  char* ws = (char*)d_ws;
  unsigned short* wp  = (unsigned short*)(ws);                 //  8 MB  permuted W_hh^T bf16
  unsigned short* wip = (unsigned short*)(ws + 8388608);       //  256KB permuted W_ih^T bf16
  unsigned short* xb  = (unsigned short*)(ws + 8650752);       //  7 MB  x bf16 [T][B][32]
  unsigned short* h0  = (unsigned short*)(ws + 15990784);      //  8 MB
  unsigned short* h1  = (unsigned short*)(ws + 24379392);      //  8 MB
  float*          cst = (float*)(ws + 32768000);               // 16 MB fp32 cell state

  hipLaunchKernelGGL(conv_x_kernel,  dim3(448), dim3(256), 0, stream, x, xb);
  hipLaunchKernelGGL(perm_whh_kernel, dim3(256), dim3(256), 0, stream, whh, wp);
  hipLaunchKernelGGL(perm_wih_kernel, dim3(256), dim3(256), 0, stream, wih, wip);

  unsigned short* hb[2] = {h0, h1};
  for (int t = 0; t < T_; ++t) {
    unsigned short* hn = hb[t & 1];
    unsigned short* hp = hb[(t & 1) ^ 1];
    hipLaunchKernelGGL(lstm_step_kernel, dim3(256), dim3(512), 0, stream,
                       hp, wp, xb + (size_t)t * (B_ * 32), wip, bias, cst, hn,
                       (t == 0) ? 1 : 0);
  }
  hipLaunchKernelGGL(cls_kernel, dim3(1024), dim3(256), 0, stream, hb[1], wc, bc, out);
}

// Round 9
// 1066.287 us; speedup vs baseline: 1.0804x; 1.0804x over previous
//
#include <hip/hip_runtime.h>
#include <hip/hip_fp16.h>
#include <stdint.h>

#define GLOBAL_AS __attribute__((address_space(1)))
#define LDS_AS    __attribute__((address_space(3)))

typedef __attribute__((ext_vector_type(8))) short  short8;   // 8 bf16 = 4 VGPRs
typedef __attribute__((ext_vector_type(4))) float  floatx4;

static constexpr int B_   = 4096;
static constexpr int T_   = 28;
static constexpr int IN_  = 28;
static constexpr int H_   = 1024;
static constexpr int G4_  = 4096;   // 4*H
static constexpr int OUT_ = 10;
static constexpr int NT_  = 16;     // K-tiles of 64 over H=1024

// ---------- small helpers ----------
__device__ __forceinline__ float bf2f(unsigned short u) {
  union { uint32_t i; float f; } v; v.i = ((uint32_t)u) << 16; return v.f;
}
__device__ __forceinline__ unsigned short f2bf(float f) {  // RTNE
  union { float f; uint32_t i; } v; v.f = f;
  uint32_t x = v.i;
  uint32_t lsb = (x >> 16) & 1u;
  x += 0x7fffu + lsb;
  return (unsigned short)(x >> 16);
}
__device__ __forceinline__ float sigm(float x) {
  return __builtin_amdgcn_rcpf(1.f + __builtin_amdgcn_exp2f(-1.4426950408889634f * x));
}
__device__ __forceinline__ float tanh_f(float x) {
  return 1.f - 2.f * __builtin_amdgcn_rcpf(1.f + __builtin_amdgcn_exp2f(2.8853900817779268f * x));
}
__device__ __forceinline__ void stage16(const unsigned short* g, unsigned short* l) {
  __builtin_amdgcn_global_load_lds(
      (const GLOBAL_AS uint32_t*)g, (LDS_AS uint32_t*)l, 16, 0, 0);
}

// ---------- prologue: x -> bf16 [T][B][32] (k padded 28->32 with zeros) ----------
__global__ __launch_bounds__(256) void conv_x_kernel(const float* __restrict__ x,
                                                     unsigned short* __restrict__ xb) {
  int row = blockIdx.x * 256 + threadIdx.x;   // row = t*4096 + b
  int t  = row >> 12;
  int bb = row & 4095;
  const float* src = x + (bb * T_ + t) * IN_;
  unsigned short* dst = xb + row * 32;
#pragma unroll
  for (int k = 0; k < IN_; ++k) dst[k] = f2bf(src[k]);
  dst[28] = 0; dst[29] = 0; dst[30] = 0; dst[31] = 0;
}

// ---------- prologue: W_hh [1024][4096] fp32 -> Wp [4096][1024] bf16, transposed+interleaved ----------
// permuted n = g64*64 + gate*16 + hw  <->  orig col = gate*1024 + g64*16 + hw
__global__ __launch_bounds__(256) void perm_whh_kernel(const float* __restrict__ whh,
                                                       unsigned short* __restrict__ wp) {
  __shared__ float lds[64][17];
  int g64  = blockIdx.x >> 2;
  int gate = blockIdx.x & 3;
  int oc0  = gate * H_ + g64 * 16;
  int n0   = g64 * 64 + gate * 16;
  int tid  = threadIdx.x;
  for (int kc = 0; kc < 16; ++kc) {
    int k0 = kc * 64;
    __syncthreads();
#pragma unroll
    for (int e = 0; e < 4; ++e) {
      int idx = e * 256 + tid;
      int k = idx >> 4, cc = idx & 15;
      lds[k][cc] = whh[(k0 + k) * G4_ + oc0 + cc];
    }
    __syncthreads();
#pragma unroll
    for (int e = 0; e < 4; ++e) {
      int idx = e * 256 + tid;
      int n = idx >> 6, kk = idx & 63;
      wp[(n0 + n) * H_ + k0 + kk] = f2bf(lds[kk][n]);
    }
  }
}

// ---------- prologue: W_ih [28][4096] -> Wip [4096][32] bf16 transposed+interleaved ----------
__global__ __launch_bounds__(256) void perm_wih_kernel(const float* __restrict__ wih,
                                                       unsigned short* __restrict__ wip) {
  __shared__ float lds[28][17];
  int g64  = blockIdx.x >> 2;
  int gate = blockIdx.x & 3;
  int oc0  = gate * H_ + g64 * 16;
  int n0   = g64 * 64 + gate * 16;
  int tid  = threadIdx.x;
  for (int idx = tid; idx < 448; idx += 256) {
    int k = idx >> 4, cc = idx & 15;
    lds[k][cc] = wih[k * G4_ + oc0 + cc];
  }
  __syncthreads();
#pragma unroll
  for (int e = 0; e < 2; ++e) {
    int idx = e * 256 + tid;
    int n = idx >> 5, kk = idx & 31;
    wip[(n0 + n) * 32 + kk] = (kk < IN_) ? f2bf(lds[kk][n]) : (unsigned short)0;
  }
}

// ============ LSTM step: 256x128 tile, single-buffer LDS (48 KB), 2 blocks/CU ============
// 8 waves (4M x 2N), wave-tile 64x64, BK=64. m97-style 2-barrier loop:
// {reads+MFMA; BAR; stage kt+1; vmcnt(0); BAR}. Staging stall covered by the OTHER
// resident block (cross-block TLP -- the mechanism all 1-block/CU schedules lacked).
// VGPR budget <=128 for 16 waves/CU: acc 64 + a[4][2] 32 + b[2][2] 16 (two B passes).
// c-state fp16 in global. T2 swizzle via pre-swizzled global source, as before.
__global__ __launch_bounds__(512, 4) void lstm_step_kernel(
    const unsigned short* __restrict__ hprev,   // [B][H] bf16
    const unsigned short* __restrict__ wp,      // [4096][1024] bf16 (permuted^T)
    const unsigned short* __restrict__ xbt,     // [B][32] bf16 (this t)
    const unsigned short* __restrict__ wip,     // [4096][32] bf16 (permuted^T)
    const float* __restrict__ bias,             // [4096] original gate order
    unsigned short* __restrict__ cst,           // [B][H] fp16 cell state
    unsigned short* __restrict__ hnext,         // [B][H] bf16
    int first) {
  __shared__ __align__(16) unsigned short lds[24576];   // 48 KB: A[256][64] | B[128][64]

  const int tid = threadIdx.x;           // 0..511
  const int w   = tid >> 6;              // wave 0..7
  const int l   = tid & 63;
  const int wm  = w >> 1;                // 0..3  (M quarter, 64 rows)
  const int wn  = w & 1;                 // 0..1  (N half, 64 cols)
  const int lc  = l & 15;
  const int lk  = l >> 4;                // 0..3

  // XCD-aware swizzle: 8x8 (bx,by) rectangle per XCD (bijective, 512 = 8 XCD * 64)
  const int hid = blockIdx.x;
  const int xcd = hid & 7, q = hid >> 3;           // q 0..63
  const int bx  = (xcd & 1) * 8 + (q & 7);         // 0..15
  const int by  = (xcd >> 1) * 8 + (q >> 3);       // 0..31
  const int m0  = bx * 256;              // batch rows
  const int n0  = by * 128;              // permuted gate cols

  const int swz  = (lc & 7) << 4;        // ds_read byte swizzle (128 B rows)
  const int swzx = (lc & 3) << 4;        // x tiles (64 B rows)

  // ---- staging per-thread constants ----
  const int r8  = tid >> 3;              // chunk-local row 0..63
  const int c8  = (tid & 7) * 8;         // ushort col within 64
  const int c8s = c8 ^ ((r8 & 7) * 8);   // pre-swizzled source col
  const int rx   = tid >> 2;             // x chunk-local row 0..127
  const int cx8s = ((tid & 3) * 8) ^ ((rx & 3) * 8);

  auto stageA = [&](int kt, int i) {     // A chunk i: rows i*64..., dst 0..16384 ushorts
    stage16(hprev + (size_t)(m0 + i * 64 + r8) * H_ + kt * 64 + c8s,
            lds + i * 4096 + tid * 8);
  };
  auto stageB = [&](int kt, int j) {     // B chunk j: cols j*64..., dst 16384..24576
    stage16(wp + (size_t)(n0 + j * 64 + r8) * H_ + kt * 64 + c8s,
            lds + 16384 + j * 4096 + tid * 8);
  };
  auto stageXA = [&](int half) {         // XA: [256][32] at ushort 0
    stage16(xbt + (size_t)(m0 + half * 128 + rx) * 32 + cx8s,
            lds + half * 4096 + tid * 8);
  };
  auto stageXB = [&]() {                 // XB: [128][32] at ushort 8192
    stage16(wip + (size_t)(n0 + rx) * 32 + cx8s,
            lds + 8192 + tid * 8);
  };
  auto ldsr = [&](int byteoff) -> short8 {
    return *reinterpret_cast<const short8*>(reinterpret_cast<const char*>(lds) + byteoff);
  };

  floatx4 acc[4][4];                     // 64 VGPR: [mf][nf], wave-tile 64x64
#pragma unroll
  for (int i = 0; i < 4; ++i)
#pragma unroll
    for (int j = 0; j < 4; ++j) acc[i][j] = (floatx4){0.f, 0.f, 0.f, 0.f};

  short8 a[4][2];                        // 32 VGPR: all A for this wave's 64 rows
  short8 b[2][2];                        // 16 VGPR: one B pass (2 n-frags)

#define LOAD_A                                                                       \
  _Pragma("unroll") for (int m_ = 0; m_ < 4; ++m_)                                   \
  _Pragma("unroll") for (int k_ = 0; k_ < 2; ++k_)                                   \
    a[m_][k_] = ldsr((wm * 64 + m_ * 16 + lc) * 128 + ((k_ * 64 + lk * 16) ^ swz));

#define LOAD_B(P)                                                                    \
  _Pragma("unroll") for (int n_ = 0; n_ < 2; ++n_)                                   \
  _Pragma("unroll") for (int k_ = 0; k_ < 2; ++k_)                                   \
    b[n_][k_] = ldsr(32768 + (wn * 64 + ((P) * 2 + n_) * 16 + lc) * 128 +            \
                     ((k_ * 64 + lk * 16) ^ swz));

#define MFMA_P(P)                                                                    \
  __builtin_amdgcn_s_setprio(1);                                                     \
  _Pragma("unroll") for (int m_ = 0; m_ < 4; ++m_)                                   \
  _Pragma("unroll") for (int n_ = 0; n_ < 2; ++n_)                                   \
  _Pragma("unroll") for (int k_ = 0; k_ < 2; ++k_)                                   \
    acc[m_][(P) * 2 + n_] = __builtin_amdgcn_mfma_f32_16x16x32_bf16(                 \
        a[m_][k_], b[n_][k_], acc[m_][(P) * 2 + n_], 0, 0, 0);                       \
  __builtin_amdgcn_s_setprio(0);

#define BAR_ONLY                                                                     \
  __builtin_amdgcn_sched_barrier(0);                                                 \
  __builtin_amdgcn_s_barrier();                                                      \
  __builtin_amdgcn_sched_barrier(0);

#define BAR_VM0                                                                      \
  __builtin_amdgcn_sched_barrier(0);                                                 \
  asm volatile("s_waitcnt vmcnt(0)" ::: "memory");                                   \
  __builtin_amdgcn_s_barrier();                                                      \
  __builtin_amdgcn_sched_barrier(0);

  // ---- x phase: stage, drain, MFMA (K=32) ----
  stageXA(0); stageXA(1); stageXB();
  BAR_VM0
  {
    short8 xb4[4];
#pragma unroll
    for (int nf = 0; nf < 4; ++nf)
      xb4[nf] = ldsr(16384 + (wn * 64 + nf * 16 + lc) * 64 + ((lk * 16) ^ swzx));
    __builtin_amdgcn_s_setprio(1);
#pragma unroll
    for (int mf = 0; mf < 4; ++mf) {
      short8 xa = ldsr((wm * 64 + mf * 16 + lc) * 64 + ((lk * 16) ^ swzx));
#pragma unroll
      for (int nf = 0; nf < 4; ++nf)
        acc[mf][nf] = __builtin_amdgcn_mfma_f32_16x16x32_bf16(xa, xb4[nf], acc[mf][nf], 0, 0, 0);
    }
    __builtin_amdgcn_s_setprio(0);
  }

  if (!first) {
    BAR_ONLY                                   // all waves consumed x (reads retired)
    // ---- tile 0 stage ----
#pragma unroll
    for (int i = 0; i < 4; ++i) stageA(0, i);
    stageB(0, 0); stageB(0, 1);
    BAR_VM0
    // ---- main loop: m97-style single-buffer, 2 barriers/tile, TLP covers the stall ----
    for (int kt = 0; kt < NT_; ++kt) {
      LOAD_A
      LOAD_B(0)
      MFMA_P(0)
      LOAD_B(1)
      MFMA_P(1)
      if (kt + 1 < NT_) {
        BAR_ONLY                               // all waves' tile-kt reads retired
#pragma unroll
        for (int i = 0; i < 4; ++i) stageA(kt + 1, i);
        stageB(kt + 1, 0); stageB(kt + 1, 1);
        BAR_VM0                                // tile kt+1 landed
      }
    }
  }

  // ---- epilogue: frag nf == gate; fused LSTM cell update; c in fp16 ----
  const int jj  = (by * 2 + wn) * 16 + lc;     // h column 0..1023
  const float bi  = bias[jj];
  const float bf_ = bias[H_ + jj];
  const float bg_ = bias[2 * H_ + jj];
  const float bo_ = bias[3 * H_ + jj];
#pragma unroll
  for (int mf = 0; mf < 4; ++mf) {
    const int rbase = m0 + wm * 64 + mf * 16 + lk * 4;
#pragma unroll
    for (int r = 0; r < 4; ++r) {
      const size_t idx = (size_t)(rbase + r) * H_ + jj;
      float ig = sigm(acc[mf][0][r] + bi);
      float fg = sigm(acc[mf][1][r] + bf_);
      float gg = tanh_f(acc[mf][2][r] + bg_);
      float og = sigm(acc[mf][3][r] + bo_);
      float cp = first ? 0.f : __half2float(__ushort_as_half(cst[idx]));
      float cn = fg * cp + ig * gg;
      cst[idx] = __half_as_ushort(__float2half(cn));
      hnext[idx] = f2bf(og * tanh_f(cn));
    }
  }
#undef LOAD_A
#undef LOAD_B
#undef MFMA_P
#undef BAR_ONLY
#undef BAR_VM0
}

// ---------- classifier: out = h @ Wc + bc ----------
__global__ __launch_bounds__(256) void cls_kernel(const unsigned short* __restrict__ h,
                                                  const float* __restrict__ wc,
                                                  const float* __restrict__ bc,
                                                  float* __restrict__ out) {
  int w = threadIdx.x >> 6, l = threadIdx.x & 63;
  int row = blockIdx.x * 4 + w;
  float acc[OUT_];
#pragma unroll
  for (int o = 0; o < OUT_; ++o) acc[o] = 0.f;
  const unsigned short* hr = h + row * H_;
  for (int k = l; k < H_; k += 64) {
    float hv = bf2f(hr[k]);
#pragma unroll
    for (int o = 0; o < OUT_; ++o) acc[o] += hv * wc[k * OUT_ + o];
  }
#pragma unroll
  for (int o = 0; o < OUT_; ++o) {
    float v = acc[o];
#pragma unroll
    for (int s = 32; s > 0; s >>= 1) v += __shfl_down(v, s, 64);
    if (l == 0) out[row * OUT_ + o] = v + bc[o];
  }
}

extern "C" void kernel_launch(void* const* d_in, const int* in_sizes, int n_in,
                              void* d_out, int out_size, void* d_ws, size_t ws_size,
                              hipStream_t stream) {
  const float* x    = (const float*)d_in[0];
  const float* wih  = (const float*)d_in[1];
  const float* whh  = (const float*)d_in[2];
  const float* bias = (const float*)d_in[3];
  const float* wc   = (const float*)d_in[4];
  const float* bc   = (const float*)d_in[5];
  float* out = (float*)d_out;

  char* ws = (char*)d_ws;
  unsigned short* wp  = (unsigned short*)(ws);                 //  8 MB  permuted W_hh^T bf16
  unsigned short* wip = (unsigned short*)(ws + 8388608);       //  256KB permuted W_ih^T bf16
  unsigned short* xb  = (unsigned short*)(ws + 8650752);       //  7 MB  x bf16 [T][B][32]
  unsigned short* h0  = (unsigned short*)(ws + 15990784);      //  8 MB
  unsigned short* h1  = (unsigned short*)(ws + 24379392);      //  8 MB
  unsigned short* cst = (unsigned short*)(ws + 32768000);      //  8 MB  fp16 cell state

  hipLaunchKernelGGL(conv_x_kernel,  dim3(448), dim3(256), 0, stream, x, xb);
  hipLaunchKernelGGL(perm_whh_kernel, dim3(256), dim3(256), 0, stream, whh, wp);
  hipLaunchKernelGGL(perm_wih_kernel, dim3(256), dim3(256), 0, stream, wih, wip);

  unsigned short* hb[2] = {h0, h1};
  for (int t = 0; t < T_; ++t) {
    unsigned short* hn = hb[t & 1];
    unsigned short* hp = hb[(t & 1) ^ 1];
    hipLaunchKernelGGL(lstm_step_kernel, dim3(512), dim3(512), 0, stream,
                       hp, wp, xb + (size_t)t * (B_ * 32), wip, bias, cst, hn,
                       (t == 0) ? 1 : 0);
  }
  hipLaunchKernelGGL(cls_kernel, dim3(1024), dim3(256), 0, stream, hb[1], wc, bc, out);
}